// Round 8
// baseline (143.436 us; speedup 1.0000x reference)
//
#include <hip/hip_runtime.h>
#include <cstdint>
#include <cstddef>

#define D_MODEL 512
#define SEQ_T 2048
#define NHEADS 8
#define HDIM 64

typedef __attribute__((ext_vector_type(8))) short bf16x8;
typedef __attribute__((ext_vector_type(4))) float f32x4;

__device__ __forceinline__ unsigned short f2bf(float f) {
  unsigned int u = __float_as_uint(f);
  u += 0x7FFFu + ((u >> 16) & 1u);
  return (unsigned short)(u >> 16);
}

// pack two f32 -> two bf16 in one uint (round via +0x8000, v_perm)
__device__ __forceinline__ unsigned int pack_bf16(float lo, float hi) {
  unsigned int a = __float_as_uint(lo) + 0x8000u;
  unsigned int b = __float_as_uint(hi) + 0x8000u;
  return __builtin_amdgcn_perm(b, a, 0x07060302u);
}

// Q pre-scaled by 1/sqrt(64) * log2(e) so softmax runs in exp2 domain.
#define QSCALE 0.18033688011112043f
// fixed softmax shift: p = exp2(s - SSHIFT); common factor cancels in O/l.
#define SSHIFT 16.0f

// async global->LDS, 16B per lane. LDS dest = wave-uniform base + lane*16.
__device__ __forceinline__ void async_lds16(const unsigned short* g,
                                            unsigned short* l) {
  __builtin_amdgcn_global_load_lds(
      (const __attribute__((address_space(1))) void*)g,
      (__attribute__((address_space(3))) void*)l, 16, 0, 0);
}

// ---------------------------------------------------------------------------
// Fused prep: [0,2048) cast x -> bf16; [2048,2240) transpose W_qkv;
// [2240,2304) transpose W_out.
// ---------------------------------------------------------------------------
__global__ __launch_bounds__(256) void prep_kernel(
    const float* __restrict__ x, const float* __restrict__ W_qkv,
    const float* __restrict__ W_out, unsigned short* __restrict__ xb,
    unsigned short* __restrict__ Wqkt, unsigned short* __restrict__ Wot) {
  __shared__ float tile[64][65];
  const int bid = blockIdx.x;
  if (bid < 2048) {
    int i = (bid * 256 + threadIdx.x) * 8;
    float4 a = *(const float4*)(x + i);
    float4 b = *(const float4*)(x + i + 4);
    ushort4 lo = {f2bf(a.x), f2bf(a.y), f2bf(a.z), f2bf(a.w)};
    ushort4 hi = {f2bf(b.x), f2bf(b.y), f2bf(b.z), f2bf(b.w)};
    *(ushort4*)(xb + i) = lo;
    *(ushort4*)(xb + i + 4) = hi;
    return;
  }
  const float* src;
  unsigned short* dst;
  int R = 512, C, c0, r0;
  if (bid < 2048 + 192) {
    int t = bid - 2048;
    C = 1536; c0 = (t % 24) * 64; r0 = (t / 24) * 64;
    src = W_qkv; dst = Wqkt;
  } else {
    int t = bid - 2240;
    C = 512; c0 = (t & 7) * 64; r0 = (t >> 3) * 64;
    src = W_out; dst = Wot;
  }
  for (int i = threadIdx.x; i < 64 * 64; i += 256) {
    int r = i >> 6, c = i & 63;
    tile[r][c] = src[(size_t)(r0 + r) * C + c0 + c];
  }
  __syncthreads();
  for (int i = threadIdx.x; i < 64 * 64; i += 256) {
    int c = i >> 6, r = i & 63;
    dst[(size_t)(c0 + c) * R + r0 + r] = f2bf(tile[r][c]);
  }
}

// ---------------------------------------------------------------------------
// Kernel 1: QKV projection, bf16 MFMA. 128x128 tile, BK=64, XOR-swizzled
// LDS. Epilogue: Q -> [bh][d][t] transposed packed (pre-scaled); V ->
// [bh][dv][t] packed; K -> [bh][t][d] scalar. (unchanged from r7)
// ---------------------------------------------------------------------------
__global__ __launch_bounds__(256) void gemm_qkv_mfma(
    const unsigned short* __restrict__ xb, const unsigned short* __restrict__ Wt,
    const float* __restrict__ bias, unsigned short* __restrict__ Qtb,
    unsigned short* __restrict__ Kb, unsigned short* __restrict__ Vtb) {
  __shared__ unsigned short As[128 * 64];
  __shared__ unsigned short Bs[128 * 64];
  const int tid = threadIdx.x;
  const int w = tid >> 6, lane = tid & 63;
  const int quad = lane >> 4, l15 = lane & 15;
  const int wm = w >> 1, wn = w & 1;
  const int m0 = blockIdx.x * 128, n0 = blockIdx.y * 128;

  const int srow = tid >> 3;
  const int schunk = (tid & 7) ^ (srow & 7);
  const unsigned short* ga = xb + (size_t)(m0 + srow) * 512 + schunk * 8;
  const unsigned short* gb = Wt + (size_t)(n0 + srow) * 512 + schunk * 8;
  unsigned short* lA = As + tid * 8;
  unsigned short* lB = Bs + tid * 8;

  f32x4 acc[4][4] = {};
  for (int k0 = 0; k0 < 512; k0 += 64) {
#pragma unroll
    for (int rr = 0; rr < 4; ++rr) {
      async_lds16(ga + (size_t)rr * 32 * 512 + k0, lA + rr * 2048);
      async_lds16(gb + (size_t)rr * 32 * 512 + k0, lB + rr * 2048);
    }
    __syncthreads();
    bf16x8 af[4][2], bfr[4][2];
#pragma unroll
    for (int mb = 0; mb < 4; ++mb) {
      int row = wm * 64 + mb * 16 + l15;
#pragma unroll
      for (int kk = 0; kk < 2; ++kk) {
        int slot = (kk * 4 + quad) ^ (row & 7);
        af[mb][kk] = *(const bf16x8*)&As[row * 64 + slot * 8];
      }
    }
#pragma unroll
    for (int nb = 0; nb < 4; ++nb) {
      int row = wn * 64 + nb * 16 + l15;
#pragma unroll
      for (int kk = 0; kk < 2; ++kk) {
        int slot = (kk * 4 + quad) ^ (row & 7);
        bfr[nb][kk] = *(const bf16x8*)&Bs[row * 64 + slot * 8];
      }
    }
#pragma unroll
    for (int mb = 0; mb < 4; ++mb)
#pragma unroll
      for (int nb = 0; nb < 4; ++nb) {
        acc[mb][nb] = __builtin_amdgcn_mfma_f32_16x16x32_bf16(
            af[mb][0], bfr[nb][0], acc[mb][nb], 0, 0, 0);
        acc[mb][nb] = __builtin_amdgcn_mfma_f32_16x16x32_bf16(
            af[mb][1], bfr[nb][1], acc[mb][nb], 0, 0, 0);
      }
    __syncthreads();
  }

  const int cbase = n0 + wn * 64;
  const int three = cbase >> 9;
  const int h = (cbase >> 6) & 7;
  const int bh = ((m0 >> 11) << 3) + h;
  const int t0 = (m0 & 2047) + wm * 64;
  float bv[4];
#pragma unroll
  for (int nb = 0; nb < 4; ++nb) bv[nb] = bias[cbase + nb * 16 + l15];

  if (three == 0) {
#pragma unroll
    for (int mb = 0; mb < 4; ++mb)
#pragma unroll
      for (int nb = 0; nb < 4; ++nb) {
        int trow = t0 + mb * 16 + quad * 4;
        ushort4 v = {f2bf((acc[mb][nb][0] + bv[nb]) * QSCALE),
                     f2bf((acc[mb][nb][1] + bv[nb]) * QSCALE),
                     f2bf((acc[mb][nb][2] + bv[nb]) * QSCALE),
                     f2bf((acc[mb][nb][3] + bv[nb]) * QSCALE)};
        *(ushort4*)(Qtb + ((size_t)bh * HDIM + nb * 16 + l15) * SEQ_T + trow) = v;
      }
  } else if (three == 2) {
#pragma unroll
    for (int mb = 0; mb < 4; ++mb)
#pragma unroll
      for (int nb = 0; nb < 4; ++nb) {
        int trow = t0 + mb * 16 + quad * 4;
        ushort4 v = {f2bf(acc[mb][nb][0] + bv[nb]), f2bf(acc[mb][nb][1] + bv[nb]),
                     f2bf(acc[mb][nb][2] + bv[nb]), f2bf(acc[mb][nb][3] + bv[nb])};
        *(ushort4*)(Vtb + ((size_t)bh * HDIM + nb * 16 + l15) * SEQ_T + trow) = v;
      }
  } else {
#pragma unroll
    for (int mb = 0; mb < 4; ++mb)
#pragma unroll
      for (int nb = 0; nb < 4; ++nb)
#pragma unroll
        for (int r = 0; r < 4; ++r) {
          int trow = t0 + mb * 16 + quad * 4 + r;
          Kb[((size_t)bh * SEQ_T + trow) * HDIM + nb * 16 + l15] =
              f2bf(acc[mb][nb][r] + bv[nb]);
        }
  }
}

// ---------------------------------------------------------------------------
// Kernel 2 (v6): causal flash attention, 128 q-rows/block (2 halves/wave).
// K/V fragments loaded once per tile, reused for both Q halves -> per-tile
// MFMA:LDS-read ratio 36:20 (was 18:18). Last two tiles peeled: tile 2qt =
// h0-diag + h1-full; tile 2qt+1 = h0-skip + h1-diag. Balanced pairing
// qt {15-k, k} -> 34 tiles per CU slot. LDS 48 KB -> 3 blocks/CU.
// ---------------------------------------------------------------------------
__global__ __launch_bounds__(256, 3) void attn_mfma6(
    const unsigned short* __restrict__ Qtb, const unsigned short* __restrict__ Kb,
    const unsigned short* __restrict__ Vtb, unsigned short* __restrict__ AOb) {
  __shared__ __align__(16) unsigned short Ks[2][64 * 64];
  __shared__ __align__(16) unsigned short Vs[2][64 * 64];
  __shared__ __align__(16) unsigned short Pt[4 * 2048];
  const int tid = threadIdx.x;
  const int w = tid >> 6, lane = tid & 63;
  const int quad = lane >> 4, l15 = lane & 15;

  // 512 blocks: xcd swizzle; first 256 get qt 15..8 (longest), then 0..7.
  const int bid = blockIdx.x;
  const int xcd = bid & 7;
  const int rest = bid >> 3;
  const int c = rest & 31, g = rest >> 5;
  const int bh = xcd + 8 * (c & 3);
  const int kq = c >> 2;
  const int qt = g ? kq : (15 - kq);

  const unsigned short* kbase = Kb + (size_t)bh * SEQ_T * HDIM;
  const unsigned short* vbase = Vtb + (size_t)bh * HDIM * SEQ_T;
  const int sr = tid >> 3;
  const int lc = tid & 7;
  const int scol = lc * 8;
  const int swc = (lc ^ (sr & 7)) * 8;

  // Q B-fragments, both halves, from transposed Qtb[bh][d][t]
  bf16x8 qf[2][2];
#pragma unroll
  for (int h = 0; h < 2; ++h) {
    unsigned short qraw[16];
    const unsigned short* qp = Qtb + ((size_t)bh * HDIM + quad * 8) * SEQ_T +
                               qt * 128 + h * 64 + w * 16 + l15;
#pragma unroll
    for (int jj = 0; jj < 8; ++jj) {
      qraw[jj] = qp[(size_t)jj * SEQ_T];
      qraw[8 + jj] = qp[(size_t)(32 + jj) * SEQ_T];
    }
    qf[h][0] = *(const bf16x8*)qraw;
    qf[h][1] = *(const bf16x8*)(qraw + 8);
  }
  const short oneb = (short)0x3F80;
  const bf16x8 ones = {oneb, oneb, oneb, oneb, oneb, oneb, oneb, oneb};

  f32x4 O[2][4];
  f32x4 l_acc[2];
#pragma unroll
  for (int h = 0; h < 2; ++h) {
    l_acc[h] = (f32x4){0.f, 0.f, 0.f, 0.f};
#pragma unroll
    for (int nbd = 0; nbd < 4; ++nbd) O[h][nbd] = (f32x4){0.f, 0.f, 0.f, 0.f};
  }
  const int q_rel = w * 16 + l15;
  const int r7m = l15 & 7;

  uint4 rk0, rk1, rv0, rv1;
  {
    const unsigned short* kp = kbase + (size_t)sr * 64 + scol;
    rk0 = *(const uint4*)kp;
    rk1 = *(const uint4*)(kp + 32 * 64);
    const unsigned short* vp = vbase + (size_t)sr * SEQ_T + scol;
    rv0 = *(const uint4*)vp;
    rv1 = *(const uint4*)(vp + 32 * SEQ_T);
  }
  *(uint4*)&Ks[0][sr * 64 + swc] = rk0;
  *(uint4*)&Ks[0][(sr + 32) * 64 + swc] = rk1;
  *(uint4*)&Vs[0][sr * 64 + swc] = rv0;
  *(uint4*)&Vs[0][(sr + 32) * 64 + swc] = rv1;
  __syncthreads();

  auto prefetch = [&](int nkt) {
    const unsigned short* kp = kbase + (size_t)(nkt * 64 + sr) * 64 + scol;
    rk0 = *(const uint4*)kp;
    rk1 = *(const uint4*)(kp + 32 * 64);
    const unsigned short* vp = vbase + (size_t)sr * SEQ_T + nkt * 64 + scol;
    rv0 = *(const uint4*)vp;
    rv1 = *(const uint4*)(vp + 32 * SEQ_T);
  };
  auto commit = [&](int nxt) {
    *(uint4*)&Ks[nxt][sr * 64 + swc] = rk0;
    *(uint4*)&Ks[nxt][(sr + 32) * 64 + swc] = rk1;
    *(uint4*)&Vs[nxt][sr * 64 + swc] = rv0;
    *(uint4*)&Vs[nxt][(sr + 32) * 64 + swc] = rv1;
  };

  // mode: 0 = full, 1 = diagonal-masked, 2 = skip
  auto tile_body = [&](int cur, int mode0, int mode1) {
    const int lim0 = (mode0 == 2) ? 0 : ((mode0 == 1) ? (w + 1) : 4);
    const int lim1 = (mode1 == 2) ? 0 : ((mode1 == 1) ? (w + 1) : 4);
    f32x4 S0[4], S1[4];
#pragma unroll
    for (int nb = 0; nb < 4; ++nb) {
      const int row = nb * 16 + l15;
      bf16x8 k0 = *(const bf16x8*)&Ks[cur][row * 64 + ((quad ^ r7m) * 8)];
      bf16x8 k1 = *(const bf16x8*)&Ks[cur][row * 64 + (((quad + 4) ^ r7m) * 8)];
      if (nb < lim0) {
        f32x4 z = {0.f, 0.f, 0.f, 0.f};
        z = __builtin_amdgcn_mfma_f32_16x16x32_bf16(k0, qf[0][0], z, 0, 0, 0);
        S0[nb] = __builtin_amdgcn_mfma_f32_16x16x32_bf16(k1, qf[0][1], z, 0, 0, 0);
      }
      if (nb < lim1) {
        f32x4 z = {0.f, 0.f, 0.f, 0.f};
        z = __builtin_amdgcn_mfma_f32_16x16x32_bf16(k0, qf[1][0], z, 0, 0, 0);
        S1[nb] = __builtin_amdgcn_mfma_f32_16x16x32_bf16(k1, qf[1][1], z, 0, 0, 0);
      }
    }
#pragma unroll
    for (int h = 0; h < 2; ++h) {
      f32x4* S = h ? S1 : S0;
      const int lim = h ? lim1 : lim0;
      const int mode = h ? mode1 : mode0;
#pragma unroll
      for (int nb = 0; nb < 4; ++nb) {
        int cc = 2 * nb + (quad >> 1);
        unsigned short* base = &Pt[w * 2048 + h * 1024 + l15 * 64 +
                                   ((cc ^ r7m) * 8) + (quad & 1) * 4];
        if (nb < lim) {
          float pp[4];
#pragma unroll
          for (int r = 0; r < 4; ++r) {
            float p = __builtin_amdgcn_exp2f(S[nb][r] - SSHIFT);
            if (mode == 1) {
              int key_rel = nb * 16 + quad * 4 + r;
              if (key_rel > q_rel) p = 0.f;
            }
            pp[r] = p;
          }
          uint2 pk = {pack_bf16(pp[0], pp[1]), pack_bf16(pp[2], pp[3])};
          *(uint2*)base = pk;
        } else if (mode == 1) {
          uint2 z2 = {0u, 0u};
          *(uint2*)base = z2;
        }
      }
    }
    bf16x8 pb[2][2];
    const int kpv0 = (mode0 == 1 && w < 2) ? 1 : 2;
    const int kpv1 = (mode1 == 1 && w < 2) ? 1 : 2;
    if (mode0 != 2) {
      pb[0][0] = *(const bf16x8*)&Pt[w * 2048 + l15 * 64 + ((quad ^ r7m) * 8)];
      pb[0][1] =
          *(const bf16x8*)&Pt[w * 2048 + l15 * 64 + (((quad + 4) ^ r7m) * 8)];
      l_acc[0] =
          __builtin_amdgcn_mfma_f32_16x16x32_bf16(ones, pb[0][0], l_acc[0], 0, 0, 0);
      if (kpv0 == 2)
        l_acc[0] = __builtin_amdgcn_mfma_f32_16x16x32_bf16(ones, pb[0][1],
                                                           l_acc[0], 0, 0, 0);
    }
    if (mode1 != 2) {
      pb[1][0] =
          *(const bf16x8*)&Pt[w * 2048 + 1024 + l15 * 64 + ((quad ^ r7m) * 8)];
      pb[1][1] = *(const bf16x8*)&Pt[w * 2048 + 1024 + l15 * 64 +
                                     (((quad + 4) ^ r7m) * 8)];
      l_acc[1] =
          __builtin_amdgcn_mfma_f32_16x16x32_bf16(ones, pb[1][0], l_acc[1], 0, 0, 0);
      if (kpv1 == 2)
        l_acc[1] = __builtin_amdgcn_mfma_f32_16x16x32_bf16(ones, pb[1][1],
                                                           l_acc[1], 0, 0, 0);
    }
#pragma unroll
    for (int nbd = 0; nbd < 4; ++nbd) {
      const int row = nbd * 16 + l15;
      bf16x8 v0 = *(const bf16x8*)&Vs[cur][row * 64 + ((quad ^ r7m) * 8)];
      bf16x8 v1 = *(const bf16x8*)&Vs[cur][row * 64 + (((quad + 4) ^ r7m) * 8)];
      if (mode0 != 2) {
        O[0][nbd] = __builtin_amdgcn_mfma_f32_16x16x32_bf16(v0, pb[0][0],
                                                            O[0][nbd], 0, 0, 0);
        if (kpv0 == 2)
          O[0][nbd] = __builtin_amdgcn_mfma_f32_16x16x32_bf16(
              v1, pb[0][1], O[0][nbd], 0, 0, 0);
      }
      if (mode1 != 2) {
        O[1][nbd] = __builtin_amdgcn_mfma_f32_16x16x32_bf16(v0, pb[1][0],
                                                            O[1][nbd], 0, 0, 0);
        if (kpv1 == 2)
          O[1][nbd] = __builtin_amdgcn_mfma_f32_16x16x32_bf16(
              v1, pb[1][1], O[1][nbd], 0, 0, 0);
      }
    }
  };

  // main loop: fully-visible tiles for both halves
  for (int i = 0; i < 2 * qt; ++i) {
    const int cur = i & 1;
    prefetch(i + 1);
    tile_body(cur, 0, 0);
    commit(cur ^ 1);
    __syncthreads();
  }
  // tile 2qt (buffer 0): h0 diagonal, h1 full
  prefetch(2 * qt + 1);
  tile_body(0, 1, 0);
  commit(1);
  __syncthreads();
  // tile 2qt+1 (buffer 1): h0 skip, h1 diagonal
  tile_body(1, 2, 1);

  // epilogue: both halves
  const int bb = bh >> 3, h8 = bh & 7;
#pragma unroll
  for (int h = 0; h < 2; ++h) {
    float inv = 1.0f / l_acc[h][0];
    int qrow = qt * 128 + h * 64 + q_rel;
    unsigned short* dst =
        AOb + ((size_t)bb * SEQ_T + qrow) * D_MODEL + (h8 << 6);
#pragma unroll
    for (int nbd = 0; nbd < 4; ++nbd) {
      ushort4 o4 = {f2bf(O[h][nbd][0] * inv), f2bf(O[h][nbd][1] * inv),
                    f2bf(O[h][nbd][2] * inv), f2bf(O[h][nbd][3] * inv)};
      *(ushort4*)(dst + nbd * 16 + quad * 4) = o4;
    }
  }
}

// ---------------------------------------------------------------------------
// Kernel 3: output projection, bf16 MFMA. 64x128 tile, BK=64 swizzled.
// (unchanged from r7)
// ---------------------------------------------------------------------------
__global__ __launch_bounds__(256) void gemm_out_mfma(
    const unsigned short* __restrict__ AOb, const unsigned short* __restrict__ Wot,
    const float* __restrict__ bias, float* __restrict__ out) {
  __shared__ unsigned short As[64 * 64];
  __shared__ unsigned short Bs[128 * 64];
  const int tid = threadIdx.x;
  const int w = tid >> 6, lane = tid & 63;
  const int quad = lane >> 4, l15 = lane & 15;
  const int m0 = blockIdx.x * 64, n0 = blockIdx.y * 128;

  const int srow = tid >> 3;
  const int schunk = (tid & 7) ^ (srow & 7);
  const unsigned short* ga = AOb + (size_t)(m0 + srow) * 512 + schunk * 8;
  const unsigned short* gb = Wot + (size_t)(n0 + srow) * 512 + schunk * 8;
  unsigned short* lA = As + tid * 8;
  unsigned short* lB = Bs + tid * 8;

  f32x4 acc[4][2] = {};
  for (int k0 = 0; k0 < 512; k0 += 64) {
#pragma unroll
    for (int rr = 0; rr < 2; ++rr)
      async_lds16(ga + (size_t)rr * 32 * 512 + k0, lA + rr * 2048);
#pragma unroll
    for (int rr = 0; rr < 4; ++rr)
      async_lds16(gb + (size_t)rr * 32 * 512 + k0, lB + rr * 2048);
    __syncthreads();
    bf16x8 af[4][2], bfr[2][2];
#pragma unroll
    for (int mb = 0; mb < 4; ++mb) {
      int row = mb * 16 + l15;
#pragma unroll
      for (int kk = 0; kk < 2; ++kk) {
        int slot = (kk * 4 + quad) ^ (row & 7);
        af[mb][kk] = *(const bf16x8*)&As[row * 64 + slot * 8];
      }
    }
#pragma unroll
    for (int nb = 0; nb < 2; ++nb) {
      int row = w * 32 + nb * 16 + l15;
#pragma unroll
      for (int kk = 0; kk < 2; ++kk) {
        int slot = (kk * 4 + quad) ^ (row & 7);
        bfr[nb][kk] = *(const bf16x8*)&Bs[row * 64 + slot * 8];
      }
    }
#pragma unroll
    for (int mb = 0; mb < 4; ++mb)
#pragma unroll
      for (int nb = 0; nb < 2; ++nb) {
        acc[mb][nb] = __builtin_amdgcn_mfma_f32_16x16x32_bf16(
            af[mb][0], bfr[nb][0], acc[mb][nb], 0, 0, 0);
        acc[mb][nb] = __builtin_amdgcn_mfma_f32_16x16x32_bf16(
            af[mb][1], bfr[nb][1], acc[mb][nb], 0, 0, 0);
      }
    __syncthreads();
  }

  const int cbase = n0 + w * 32;
  float bv[2];
#pragma unroll
  for (int nb = 0; nb < 2; ++nb) bv[nb] = bias[cbase + nb * 16 + l15];
#pragma unroll
  for (int mb = 0; mb < 4; ++mb)
#pragma unroll
    for (int nb = 0; nb < 2; ++nb)
#pragma unroll
      for (int r = 0; r < 4; ++r)
        out[(size_t)(m0 + mb * 16 + quad * 4 + r) * 512 + cbase + nb * 16 +
            l15] = acc[mb][nb][r] + bv[nb];
}

// ---------------------------------------------------------------------------
extern "C" void kernel_launch(void* const* d_in, const int* in_sizes, int n_in,
                              void* d_out, int out_size, void* d_ws,
                              size_t ws_size, hipStream_t stream) {
  const float* x     = (const float*)d_in[0];
  const float* W_qkv = (const float*)d_in[1];
  const float* b_qkv = (const float*)d_in[2];
  const float* W_out = (const float*)d_in[3];
  const float* b_out = (const float*)d_in[4];
  float* out = (float*)d_out;

  const size_t NX = (size_t)4 * SEQ_T * D_MODEL;        // 4,194,304
  unsigned short* xb   = (unsigned short*)d_ws;          // [8192][512]
  unsigned short* Wqkt = xb + NX;                        // [1536][512]
  unsigned short* Wot  = Wqkt + (size_t)1536 * 512;      // [512][512]
  unsigned short* Qtb  = Wot + (size_t)512 * 512;        // [bh][d][t]
  unsigned short* Kb   = Qtb + NX;                       // [bh][t][d]
  unsigned short* Vtb  = Kb + NX;                        // [bh][dv][t]
  unsigned short* AOb  = Vtb + NX;                       // [8192][512]

  prep_kernel<<<2304, 256, 0, stream>>>(x, W_qkv, W_out, xb, Wqkt, Wot);
  gemm_qkv_mfma<<<dim3(64, 12), 256, 0, stream>>>(xb, Wqkt, b_qkv, Qtb, Kb,
                                                  Vtb);
  attn_mfma6<<<dim3(512), 256, 0, stream>>>(Qtb, Kb, Vtb, AOb);
  gemm_out_mfma<<<dim3(128, 4), 256, 0, stream>>>(AOb, Wot, b_out, out);
}

// Round 9
// 137.205 us; speedup vs baseline: 1.0454x; 1.0454x over previous
//
#include <hip/hip_runtime.h>
#include <cstdint>
#include <cstddef>

#define D_MODEL 512
#define SEQ_T 2048
#define NHEADS 8
#define HDIM 64

typedef __attribute__((ext_vector_type(8))) short bf16x8;
typedef __attribute__((ext_vector_type(4))) float f32x4;

__device__ __forceinline__ unsigned short f2bf(float f) {
  unsigned int u = __float_as_uint(f);
  u += 0x7FFFu + ((u >> 16) & 1u);
  return (unsigned short)(u >> 16);
}

// pack two f32 -> two bf16 in one uint (round via +0x8000, v_perm)
__device__ __forceinline__ unsigned int pack_bf16(float lo, float hi) {
  unsigned int a = __float_as_uint(lo) + 0x8000u;
  unsigned int b = __float_as_uint(hi) + 0x8000u;
  return __builtin_amdgcn_perm(b, a, 0x07060302u);
}

// Q pre-scaled by 1/sqrt(64) * log2(e) so softmax runs in exp2 domain.
#define QSCALE 0.18033688011112043f
// fixed softmax shift: p = exp2(s - SSHIFT); common factor cancels in O/l.
#define SSHIFT 16.0f

// async global->LDS, 16B per lane. LDS dest = wave-uniform base + lane*size.
__device__ __forceinline__ void async_lds16(const unsigned short* g,
                                            unsigned short* l) {
  __builtin_amdgcn_global_load_lds(
      (const __attribute__((address_space(1))) void*)g,
      (__attribute__((address_space(3))) void*)l, 16, 0, 0);
}

// ---------------------------------------------------------------------------
// Prep: W transposes only (x cast is fused into gemm_qkv staging).
// [0,192) transpose W_qkv -> [1536][512] bf16; [192,256) W_out -> [512][512].
// ---------------------------------------------------------------------------
__global__ __launch_bounds__(256) void prep_kernel(
    const float* __restrict__ W_qkv, const float* __restrict__ W_out,
    unsigned short* __restrict__ Wqkt, unsigned short* __restrict__ Wot) {
  __shared__ float tile[64][65];
  const int bid = blockIdx.x;
  const float* src;
  unsigned short* dst;
  int R = 512, C, c0, r0;
  if (bid < 192) {
    C = 1536; c0 = (bid % 24) * 64; r0 = (bid / 24) * 64;
    src = W_qkv; dst = Wqkt;
  } else {
    int t = bid - 192;
    C = 512; c0 = (t & 7) * 64; r0 = (t >> 3) * 64;
    src = W_out; dst = Wot;
  }
  for (int i = threadIdx.x; i < 64 * 64; i += 256) {
    int r = i >> 6, c = i & 63;
    tile[r][c] = src[(size_t)(r0 + r) * C + c0 + c];
  }
  __syncthreads();
  for (int i = threadIdx.x; i < 64 * 64; i += 256) {
    int c = i >> 6, r = i & 63;
    dst[(size_t)(c0 + c) * R + r0 + r] = f2bf(tile[r][c]);
  }
}

// ---------------------------------------------------------------------------
// Kernel 1: QKV projection, bf16 MFMA. 128x128 tile, BK=64, XOR-swizzled
// LDS. A is staged DIRECTLY from fp32 x with in-register cast (fused prep);
// B (bf16 W^T) via global_load_lds. Epilogue: Q -> [bh][d][t] transposed
// packed (pre-scaled); V -> [bh][dv][t] packed; K -> [bh][t][d] scalar.
// ---------------------------------------------------------------------------
__global__ __launch_bounds__(256) void gemm_qkv_mfma(
    const float* __restrict__ x, const unsigned short* __restrict__ Wt,
    const float* __restrict__ bias, unsigned short* __restrict__ Qtb,
    unsigned short* __restrict__ Kb, unsigned short* __restrict__ Vtb) {
  __shared__ unsigned short As[128 * 64];
  __shared__ unsigned short Bs[128 * 64];
  const int tid = threadIdx.x;
  const int w = tid >> 6, lane = tid & 63;
  const int quad = lane >> 4, l15 = lane & 15;
  const int wm = w >> 1, wn = w & 1;
  const int m0 = blockIdx.x * 128, n0 = blockIdx.y * 128;

  const int srow = tid >> 3;                   // 0..31
  const int lc = tid & 7;                      // physical LDS slot
  const int clog = lc ^ (srow & 7);            // logical chunk fetched
  // A: fp32 source, manual cast+stage (slot lc holds logical chunk lc^(row&7))
  const float* gax = x + (size_t)(m0 + srow) * 512 + clog * 8;
  // B: bf16 source via async DMA (same swizzle relation as r7)
  const unsigned short* gb = Wt + (size_t)(n0 + srow) * 512 + clog * 8;
  unsigned short* lA = As + tid * 8;           // = srow*64 + lc*8
  unsigned short* lB = Bs + tid * 8;

  f32x4 acc[4][4] = {};
  for (int k0 = 0; k0 < 512; k0 += 64) {
#pragma unroll
    for (int rr = 0; rr < 4; ++rr)
      async_lds16(gb + (size_t)rr * 32 * 512 + k0, lB + rr * 2048);
#pragma unroll
    for (int rr = 0; rr < 4; ++rr) {
      const float* p = gax + (size_t)rr * 32 * 512 + k0;
      float4 a = *(const float4*)p;
      float4 b = *(const float4*)(p + 4);
      uint4 pk = {pack_bf16(a.x, a.y), pack_bf16(a.z, a.w),
                  pack_bf16(b.x, b.y), pack_bf16(b.z, b.w)};
      *(uint4*)(lA + rr * 2048) = pk;
    }
    __syncthreads();
    bf16x8 af[4][2], bfr[4][2];
#pragma unroll
    for (int mb = 0; mb < 4; ++mb) {
      int row = wm * 64 + mb * 16 + l15;
#pragma unroll
      for (int kk = 0; kk < 2; ++kk) {
        int slot = (kk * 4 + quad) ^ (row & 7);
        af[mb][kk] = *(const bf16x8*)&As[row * 64 + slot * 8];
      }
    }
#pragma unroll
    for (int nb = 0; nb < 4; ++nb) {
      int row = wn * 64 + nb * 16 + l15;
#pragma unroll
      for (int kk = 0; kk < 2; ++kk) {
        int slot = (kk * 4 + quad) ^ (row & 7);
        bfr[nb][kk] = *(const bf16x8*)&Bs[row * 64 + slot * 8];
      }
    }
#pragma unroll
    for (int mb = 0; mb < 4; ++mb)
#pragma unroll
      for (int nb = 0; nb < 4; ++nb) {
        acc[mb][nb] = __builtin_amdgcn_mfma_f32_16x16x32_bf16(
            af[mb][0], bfr[nb][0], acc[mb][nb], 0, 0, 0);
        acc[mb][nb] = __builtin_amdgcn_mfma_f32_16x16x32_bf16(
            af[mb][1], bfr[nb][1], acc[mb][nb], 0, 0, 0);
      }
    __syncthreads();
  }

  const int cbase = n0 + wn * 64;
  const int three = cbase >> 9;          // 0:Q 1:K 2:V
  const int h = (cbase >> 6) & 7;
  const int bh = ((m0 >> 11) << 3) + h;
  const int t0 = (m0 & 2047) + wm * 64;
  float bv[4];
#pragma unroll
  for (int nb = 0; nb < 4; ++nb) bv[nb] = bias[cbase + nb * 16 + l15];

  if (three == 0) {
    // Q transposed [bh][d][t], pre-scaled, packed along t
#pragma unroll
    for (int mb = 0; mb < 4; ++mb)
#pragma unroll
      for (int nb = 0; nb < 4; ++nb) {
        int trow = t0 + mb * 16 + quad * 4;
        ushort4 v = {f2bf((acc[mb][nb][0] + bv[nb]) * QSCALE),
                     f2bf((acc[mb][nb][1] + bv[nb]) * QSCALE),
                     f2bf((acc[mb][nb][2] + bv[nb]) * QSCALE),
                     f2bf((acc[mb][nb][3] + bv[nb]) * QSCALE)};
        *(ushort4*)(Qtb + ((size_t)bh * HDIM + nb * 16 + l15) * SEQ_T + trow) = v;
      }
  } else if (three == 2) {
    // V transposed [bh][dv][t], packed along t
#pragma unroll
    for (int mb = 0; mb < 4; ++mb)
#pragma unroll
      for (int nb = 0; nb < 4; ++nb) {
        int trow = t0 + mb * 16 + quad * 4;
        ushort4 v = {f2bf(acc[mb][nb][0] + bv[nb]), f2bf(acc[mb][nb][1] + bv[nb]),
                     f2bf(acc[mb][nb][2] + bv[nb]), f2bf(acc[mb][nb][3] + bv[nb])};
        *(ushort4*)(Vtb + ((size_t)bh * HDIM + nb * 16 + l15) * SEQ_T + trow) = v;
      }
  } else {
    // K row-major [bh][t][d] (attn A-fragment needs contiguous d)
#pragma unroll
    for (int mb = 0; mb < 4; ++mb)
#pragma unroll
      for (int nb = 0; nb < 4; ++nb)
#pragma unroll
        for (int r = 0; r < 4; ++r) {
          int trow = t0 + mb * 16 + quad * 4 + r;
          Kb[((size_t)bh * SEQ_T + trow) * HDIM + nb * 16 + l15] =
              f2bf(acc[mb][nb][r] + bv[nb]);
        }
  }
}

// ---------------------------------------------------------------------------
// Kernel 2 (v5, r7 proven): causal flash attention.
//  - balanced grid: each CU-slot's 4 blocks get qt {31-k,16+k,15-k,k}
//  - peeled diagonal tile; l via ones-MFMA; double-buffered swizzled LDS
//  - fixed-shift softmax p = exp2(s-16)
// ---------------------------------------------------------------------------
__global__ __launch_bounds__(256, 4) void attn_mfma5(
    const unsigned short* __restrict__ Qtb, const unsigned short* __restrict__ Kb,
    const unsigned short* __restrict__ Vtb, unsigned short* __restrict__ AOb) {
  __shared__ __align__(16) unsigned short Ks[2][64 * 64];
  __shared__ __align__(16) unsigned short Vs[2][64 * 64];
  __shared__ __align__(16) unsigned short Pt[4][16 * 64];
  const int tid = threadIdx.x;
  const int w = tid >> 6, lane = tid & 63;
  const int quad = lane >> 4, l15 = lane & 15;

  const int bid = blockIdx.x;
  const int xcd = bid & 7;
  const int j = bid >> 3;
  const int c = j & 31, g = j >> 5;
  const int k = c >> 2;
  const int bh = xcd + 8 * (c & 3);
  const int qt = (g == 0) ? (31 - k) : (g == 1) ? (16 + k)
               : (g == 2) ? (15 - k) : k;

  const unsigned short* kbase = Kb + (size_t)bh * SEQ_T * HDIM;
  const unsigned short* vbase = Vtb + (size_t)bh * HDIM * SEQ_T;
  const int sr = tid >> 3;
  const int lc = tid & 7;
  const int scol = lc * 8;
  const int swc = (lc ^ (sr & 7)) * 8;

  bf16x8 qf0, qf1;
  {
    unsigned short qraw[16];
    const unsigned short* qp =
        Qtb + ((size_t)bh * HDIM + quad * 8) * SEQ_T + qt * 64 + w * 16 + l15;
#pragma unroll
    for (int jj = 0; jj < 8; ++jj) {
      qraw[jj] = qp[(size_t)jj * SEQ_T];
      qraw[8 + jj] = qp[(size_t)(32 + jj) * SEQ_T];
    }
    qf0 = *(const bf16x8*)qraw;
    qf1 = *(const bf16x8*)(qraw + 8);
  }
  const short oneb = (short)0x3F80;
  const bf16x8 ones = {oneb, oneb, oneb, oneb, oneb, oneb, oneb, oneb};

  f32x4 O[4] = {{0.f, 0.f, 0.f, 0.f}, {0.f, 0.f, 0.f, 0.f},
                {0.f, 0.f, 0.f, 0.f}, {0.f, 0.f, 0.f, 0.f}};
  f32x4 l_acc = {0.f, 0.f, 0.f, 0.f};
  const int q_rel = w * 16 + l15;
  const int r7 = l15 & 7;

  uint4 rk0, rk1, rv0, rv1;
  {
    const unsigned short* kp = kbase + (size_t)sr * 64 + scol;
    rk0 = *(const uint4*)kp;
    rk1 = *(const uint4*)(kp + 32 * 64);
    const unsigned short* vp = vbase + (size_t)sr * SEQ_T + scol;
    rv0 = *(const uint4*)vp;
    rv1 = *(const uint4*)(vp + 32 * SEQ_T);
  }
  *(uint4*)&Ks[0][sr * 64 + swc] = rk0;
  *(uint4*)&Ks[0][(sr + 32) * 64 + swc] = rk1;
  *(uint4*)&Vs[0][sr * 64 + swc] = rv0;
  *(uint4*)&Vs[0][(sr + 32) * 64 + swc] = rv1;
  __syncthreads();

  for (int i = 0; i < qt; ++i) {
    const int cur = i & 1;
    {
      const int nkt = i + 1;
      const unsigned short* kp = kbase + (size_t)(nkt * 64 + sr) * 64 + scol;
      rk0 = *(const uint4*)kp;
      rk1 = *(const uint4*)(kp + 32 * 64);
      const unsigned short* vp = vbase + (size_t)sr * SEQ_T + nkt * 64 + scol;
      rv0 = *(const uint4*)vp;
      rv1 = *(const uint4*)(vp + 32 * SEQ_T);
    }

    f32x4 S[4];
#pragma unroll
    for (int nb = 0; nb < 4; ++nb) {
      const int row = nb * 16 + l15;
      const unsigned short* k0p = &Ks[cur][row * 64 + ((quad ^ r7) * 8)];
      const unsigned short* k1p = &Ks[cur][row * 64 + (((quad + 4) ^ r7) * 8)];
      f32x4 z = {0.f, 0.f, 0.f, 0.f};
      z = __builtin_amdgcn_mfma_f32_16x16x32_bf16(*(const bf16x8*)k0p, qf0, z,
                                                  0, 0, 0);
      S[nb] = __builtin_amdgcn_mfma_f32_16x16x32_bf16(*(const bf16x8*)k1p, qf1,
                                                      z, 0, 0, 0);
    }

#pragma unroll
    for (int nb = 0; nb < 4; ++nb) {
      float p0 = __builtin_amdgcn_exp2f(S[nb][0] - SSHIFT);
      float p1 = __builtin_amdgcn_exp2f(S[nb][1] - SSHIFT);
      float p2 = __builtin_amdgcn_exp2f(S[nb][2] - SSHIFT);
      float p3 = __builtin_amdgcn_exp2f(S[nb][3] - SSHIFT);
      int cc = 2 * nb + (quad >> 1);
      uint2 pk = {pack_bf16(p0, p1), pack_bf16(p2, p3)};
      *(uint2*)&Pt[w][l15 * 64 + ((cc ^ r7) * 8) + (quad & 1) * 4] = pk;
    }

    bf16x8 pb0 = *(const bf16x8*)&Pt[w][l15 * 64 + ((quad ^ r7) * 8)];
    bf16x8 pb1 = *(const bf16x8*)&Pt[w][l15 * 64 + (((quad + 4) ^ r7) * 8)];
    l_acc = __builtin_amdgcn_mfma_f32_16x16x32_bf16(ones, pb0, l_acc, 0, 0, 0);
    l_acc = __builtin_amdgcn_mfma_f32_16x16x32_bf16(ones, pb1, l_acc, 0, 0, 0);
#pragma unroll
    for (int nbd = 0; nbd < 4; ++nbd) {
      const int row = nbd * 16 + l15;
      const unsigned short* v0p = &Vs[cur][row * 64 + ((quad ^ r7) * 8)];
      const unsigned short* v1p = &Vs[cur][row * 64 + (((quad + 4) ^ r7) * 8)];
      O[nbd] = __builtin_amdgcn_mfma_f32_16x16x32_bf16(*(const bf16x8*)v0p, pb0,
                                                       O[nbd], 0, 0, 0);
      O[nbd] = __builtin_amdgcn_mfma_f32_16x16x32_bf16(*(const bf16x8*)v1p, pb1,
                                                       O[nbd], 0, 0, 0);
    }

    const int nxt = cur ^ 1;
    *(uint4*)&Ks[nxt][sr * 64 + swc] = rk0;
    *(uint4*)&Ks[nxt][(sr + 32) * 64 + swc] = rk1;
    *(uint4*)&Vs[nxt][sr * 64 + swc] = rv0;
    *(uint4*)&Vs[nxt][(sr + 32) * 64 + swc] = rv1;
    __syncthreads();
  }

  // diagonal tile
  {
    const int cur = qt & 1;
    const int nb_lim = w + 1;
    f32x4 S[4];
#pragma unroll
    for (int nb = 0; nb < 4; ++nb) {
      if (nb < nb_lim) {
        const int row = nb * 16 + l15;
        const unsigned short* k0p = &Ks[cur][row * 64 + ((quad ^ r7) * 8)];
        const unsigned short* k1p =
            &Ks[cur][row * 64 + (((quad + 4) ^ r7) * 8)];
        f32x4 z = {0.f, 0.f, 0.f, 0.f};
        z = __builtin_amdgcn_mfma_f32_16x16x32_bf16(*(const bf16x8*)k0p, qf0,
                                                    z, 0, 0, 0);
        S[nb] = __builtin_amdgcn_mfma_f32_16x16x32_bf16(*(const bf16x8*)k1p,
                                                        qf1, z, 0, 0, 0);
      }
    }
#pragma unroll
    for (int nb = 0; nb < 4; ++nb) {
      int cc = 2 * nb + (quad >> 1);
      if (nb < nb_lim) {
        float pp[4];
#pragma unroll
        for (int r = 0; r < 4; ++r) {
          float p = __builtin_amdgcn_exp2f(S[nb][r] - SSHIFT);
          int key_rel = nb * 16 + quad * 4 + r;
          pp[r] = (key_rel > q_rel) ? 0.f : p;
        }
        uint2 pk = {pack_bf16(pp[0], pp[1]), pack_bf16(pp[2], pp[3])};
        *(uint2*)&Pt[w][l15 * 64 + ((cc ^ r7) * 8) + (quad & 1) * 4] = pk;
      } else {
        uint2 z2 = {0u, 0u};
        *(uint2*)&Pt[w][l15 * 64 + ((cc ^ r7) * 8) + (quad & 1) * 4] = z2;
      }
    }
    const int kpv = (w >= 2) ? 2 : 1;
    bf16x8 pb0 = *(const bf16x8*)&Pt[w][l15 * 64 + ((quad ^ r7) * 8)];
    bf16x8 pb1 = *(const bf16x8*)&Pt[w][l15 * 64 + (((quad + 4) ^ r7) * 8)];
    l_acc = __builtin_amdgcn_mfma_f32_16x16x32_bf16(ones, pb0, l_acc, 0, 0, 0);
    if (kpv == 2)
      l_acc =
          __builtin_amdgcn_mfma_f32_16x16x32_bf16(ones, pb1, l_acc, 0, 0, 0);
#pragma unroll
    for (int nbd = 0; nbd < 4; ++nbd) {
      const int row = nbd * 16 + l15;
      const unsigned short* v0p = &Vs[cur][row * 64 + ((quad ^ r7) * 8)];
      O[nbd] = __builtin_amdgcn_mfma_f32_16x16x32_bf16(*(const bf16x8*)v0p, pb0,
                                                       O[nbd], 0, 0, 0);
      if (kpv == 2) {
        const unsigned short* v1p =
            &Vs[cur][row * 64 + (((quad + 4) ^ r7) * 8)];
        O[nbd] = __builtin_amdgcn_mfma_f32_16x16x32_bf16(*(const bf16x8*)v1p,
                                                         pb1, O[nbd], 0, 0, 0);
      }
    }
  }

  float inv = 1.0f / l_acc[0];
  const int bb = bh >> 3, h = bh & 7;
  int qrow = qt * 64 + q_rel;
  unsigned short* dst = AOb + ((size_t)bb * SEQ_T + qrow) * D_MODEL + (h << 6);
#pragma unroll
  for (int nbd = 0; nbd < 4; ++nbd) {
    ushort4 o4 = {f2bf(O[nbd][0] * inv), f2bf(O[nbd][1] * inv),
                  f2bf(O[nbd][2] * inv), f2bf(O[nbd][3] * inv)};
    *(ushort4*)(dst + nbd * 16 + quad * 4) = o4;
  }
}

// ---------------------------------------------------------------------------
// Kernel 3: output projection, bf16 MFMA. 64x128 tile, BK=64 swizzled.
// (unchanged from r7)
// ---------------------------------------------------------------------------
__global__ __launch_bounds__(256) void gemm_out_mfma(
    const unsigned short* __restrict__ AOb, const unsigned short* __restrict__ Wot,
    const float* __restrict__ bias, float* __restrict__ out) {
  __shared__ unsigned short As[64 * 64];
  __shared__ unsigned short Bs[128 * 64];
  const int tid = threadIdx.x;
  const int w = tid >> 6, lane = tid & 63;
  const int quad = lane >> 4, l15 = lane & 15;
  const int m0 = blockIdx.x * 64, n0 = blockIdx.y * 128;

  const int srow = tid >> 3;
  const int schunk = (tid & 7) ^ (srow & 7);
  const unsigned short* ga = AOb + (size_t)(m0 + srow) * 512 + schunk * 8;
  const unsigned short* gb = Wot + (size_t)(n0 + srow) * 512 + schunk * 8;
  unsigned short* lA = As + tid * 8;
  unsigned short* lB = Bs + tid * 8;

  f32x4 acc[4][2] = {};
  for (int k0 = 0; k0 < 512; k0 += 64) {
#pragma unroll
    for (int rr = 0; rr < 2; ++rr)
      async_lds16(ga + (size_t)rr * 32 * 512 + k0, lA + rr * 2048);
#pragma unroll
    for (int rr = 0; rr < 4; ++rr)
      async_lds16(gb + (size_t)rr * 32 * 512 + k0, lB + rr * 2048);
    __syncthreads();
    bf16x8 af[4][2], bfr[2][2];
#pragma unroll
    for (int mb = 0; mb < 4; ++mb) {
      int row = mb * 16 + l15;
#pragma unroll
      for (int kk = 0; kk < 2; ++kk) {
        int slot = (kk * 4 + quad) ^ (row & 7);
        af[mb][kk] = *(const bf16x8*)&As[row * 64 + slot * 8];
      }
    }
#pragma unroll
    for (int nb = 0; nb < 2; ++nb) {
      int row = w * 32 + nb * 16 + l15;
#pragma unroll
      for (int kk = 0; kk < 2; ++kk) {
        int slot = (kk * 4 + quad) ^ (row & 7);
        bfr[nb][kk] = *(const bf16x8*)&Bs[row * 64 + slot * 8];
      }
    }
#pragma unroll
    for (int mb = 0; mb < 4; ++mb)
#pragma unroll
      for (int nb = 0; nb < 2; ++nb) {
        acc[mb][nb] = __builtin_amdgcn_mfma_f32_16x16x32_bf16(
            af[mb][0], bfr[nb][0], acc[mb][nb], 0, 0, 0);
        acc[mb][nb] = __builtin_amdgcn_mfma_f32_16x16x32_bf16(
            af[mb][1], bfr[nb][1], acc[mb][nb], 0, 0, 0);
      }
    __syncthreads();
  }

  const int cbase = n0 + w * 32;
  float bv[2];
#pragma unroll
  for (int nb = 0; nb < 2; ++nb) bv[nb] = bias[cbase + nb * 16 + l15];
#pragma unroll
  for (int mb = 0; mb < 4; ++mb)
#pragma unroll
    for (int nb = 0; nb < 2; ++nb)
#pragma unroll
      for (int r = 0; r < 4; ++r)
        out[(size_t)(m0 + mb * 16 + quad * 4 + r) * 512 + cbase + nb * 16 +
            l15] = acc[mb][nb][r] + bv[nb];
}

// ---------------------------------------------------------------------------
extern "C" void kernel_launch(void* const* d_in, const int* in_sizes, int n_in,
                              void* d_out, int out_size, void* d_ws,
                              size_t ws_size, hipStream_t stream) {
  const float* x     = (const float*)d_in[0];
  const float* W_qkv = (const float*)d_in[1];
  const float* b_qkv = (const float*)d_in[2];
  const float* W_out = (const float*)d_in[3];
  const float* b_out = (const float*)d_in[4];
  float* out = (float*)d_out;

  const size_t NX = (size_t)4 * SEQ_T * D_MODEL;        // 4,194,304
  unsigned short* Wqkt = (unsigned short*)d_ws;          // [1536][512]
  unsigned short* Wot  = Wqkt + (size_t)1536 * 512;      // [512][512]
  unsigned short* Qtb  = Wot + (size_t)512 * 512;        // [bh][d][t]
  unsigned short* Kb   = Qtb + NX;                       // [bh][t][d]
  unsigned short* Vtb  = Kb + NX;                        // [bh][dv][t]
  unsigned short* AOb  = Vtb + NX;                       // [8192][512]

  prep_kernel<<<256, 256, 0, stream>>>(W_qkv, W_out, Wqkt, Wot);
  gemm_qkv_mfma<<<dim3(64, 12), 256, 0, stream>>>(x, Wqkt, b_qkv, Qtb, Kb,
                                                  Vtb);
  attn_mfma5<<<dim3(1024), 256, 0, stream>>>(Qtb, Kb, Vtb, AOb);
  gemm_out_mfma<<<dim3(128, 4), 256, 0, stream>>>(AOb, Wot, b_out, out);
}